// Round 6
// baseline (760.447 us; speedup 1.0000x reference)
//
#include <hip/hip_runtime.h>
#include <hip/hip_bf16.h>

#define NN 96
#define NBLK 16
#define JR 6           // rows per block
#define TT 4656        // triu length
#define LGB 291        // sigmoid outputs per block (16*291 = 4656)
#define LGP 384        // padded stride
#define NITER 50
#define SPIN_MAX (1 << 18)   // bounded spin: deadlock -> wrong answer, not hang

__device__ __forceinline__ float bf2f(__hip_bfloat16 v) { return __bfloat162float(v); }

__device__ __forceinline__ float LD(const void* p, int i, bool f32) {
  return f32 ? ((const float*)p)[i]
             : __bfloat162float(((const __hip_bfloat16*)p)[i]);
}

// Relaxed agent-scope (sc1) accessors: served at MALL, no cache maintenance.
__device__ __forceinline__ float ldA(const float* p) {
  return __hip_atomic_load(p, __ATOMIC_RELAXED, __HIP_MEMORY_SCOPE_AGENT);
}
__device__ __forceinline__ void stA(float* p, float v) {
  __hip_atomic_store(p, v, __ATOMIC_RELAXED, __HIP_MEMORY_SCOPE_AGENT);
}
__device__ __forceinline__ unsigned long long ldA64(const unsigned long long* p) {
  return __hip_atomic_load(p, __ATOMIC_RELAXED, __HIP_MEMORY_SCOPE_AGENT);
}

// Distributed-flag device barrier: no shared hot line, no RMW.
// Each block stores `target` to its own 128B-padded flag; wave 0 polls all
// NBLK flags with a single load instruction (lane b -> flag[b]) + __all.
// A block can be at most ONE barrier ahead (to pass t+1 it needs all flags
// >= t+1), so accept v in {target, target+1}: (v - target) <= 1 unsigned.
// The 0xAAAAAAAA ws-poison fails this -> no init handshake needed.
// Spin is bounded: a logic bug surfaces as wrong output, not a GPU hang.
__device__ __forceinline__ void gbar(uint32_t* flags, uint32_t target, int blk) {
  asm volatile("s_waitcnt vmcnt(0)" ::: "memory");  // our sc1 stores acked at MALL
  __syncthreads();
  if (threadIdx.x == 0)
    __hip_atomic_store(&flags[blk * 32], target, __ATOMIC_RELAXED,
                       __HIP_MEMORY_SCOPE_AGENT);
  if (threadIdx.x < 64) {
    for (int spin = 0; spin < SPIN_MAX; ++spin) {
      uint32_t v = (threadIdx.x < NBLK)
          ? __hip_atomic_load(&flags[threadIdx.x * 32], __ATOMIC_RELAXED,
                              __HIP_MEMORY_SCOPE_AGENT)
          : target;
      if (__all((v - target) <= 1u)) break;
      __builtin_amdgcn_s_sleep(1);
    }
  }
  __syncthreads();
}

__global__ __launch_bounds__(256, 1) void gvae_kernel(
    const void* __restrict__ ge,
    const void* __restrict__ adj,
    const void* __restrict__ W1,
    const void* __restrict__ b1,
    const void* __restrict__ W2,
    const void* __restrict__ b2,
    const void* __restrict__ W3,
    const void* __restrict__ b3,
    void* __restrict__ out,
    float* __restrict__ ws)
{
  __shared__ __align__(16) float t2s[NN * NN];      // 36 KB
  __shared__ __align__(16) float Ms[NN * NN];       // 36 KB
  __shared__ __align__(16) float parts[8 * JR * NN];// 18 KB
  __shared__ __align__(16) float xs[JR * NN];
  __shared__ __align__(16) float Ds[JR * NN];
  __shared__ float ges[256];
  __shared__ float frs[NN];
  __shared__ float dRs[NN];
  __shared__ float h1s[250];
  __shared__ float h2s[100];
  __shared__ int   nbr[JR * NN];
  __shared__ int   ncnt[JR];
  __shared__ float f_own[JR];
  __shared__ float red[4];
  __shared__ float s_scale;

  const int tid = threadIdx.x;
  const int blk = blockIdx.x;

  // ---- dtype sniff (wave-uniform; inputs fixed -> graph-safe) ----
  float sv = (tid < 128) ? bf2f(((const __hip_bfloat16*)W1)[tid])
                         : bf2f(((const __hip_bfloat16*)W3)[tid - 128]);
  const bool isf32 = __syncthreads_or(!(fabsf(sv) < 1e4f)) != 0;

  uint32_t* flags  = (uint32_t*)ws;      // 16 flags, 128B apart (512 u32)
  float*    normsq = ws + 512;           // 50 slots
  float*    lg2    = ws + 576;           // 16 x 384 padded sigmoid outputs
  float*    M0     = ws + 6720;          // 9216 floats, 16B aligned
  float*    M1     = ws + 6720 + NN * NN;

  // ---- P1: MLP layers 1-2, redundant per block ----
  if (blk == 0 && tid < NITER) stA(&normsq[tid], 0.0f);
  ges[tid] = LD(ge, tid, isf32);
  __syncthreads();
  if (tid < 250) {
    float acc = LD(b1, tid, isf32);
    for (int e = 0; e < 256; ++e)
      acc += ges[e] * LD(W1, e * 250 + tid, isf32);
    h1s[tid] = acc;
  }
  __syncthreads();
  if (tid < 100) {
    float acc = LD(b2, tid, isf32);
    for (int k = 0; k < 250; ++k)
      acc += h1s[k] * LD(W2, k * 100 + tid, isf32);
    h2s[tid] = fmaxf(acc, 0.0f);
  }
  __syncthreads();

  // ---- P2: sigmoid layer (291 outputs/block, sc1 stores) + adjacency ----
  for (int o = tid; o < LGB; o += 256) {
    int og = blk * LGB + o;
    float acc = LD(b3, og, isf32);
    for (int k = 0; k < 100; ++k)
      acc += h2s[k] * LD(W3, k * TT + og, isf32);
    stA(&lg2[blk * LGP + o], 1.0f / (1.0f + expf(-acc)));
  }
  if (tid < JR) {
    int ig = blk * JR + tid;
    float fsum = 1.0f;  // diag of ori forced to 1
    int c = 0;
    for (int j2 = 0; j2 < NN; ++j2) {
      if (j2 == ig) continue;
      float v = LD(adj, ig * NN + j2, isf32);
      fsum += v;
      if (v > 0.5f) nbr[tid * NN + (c++)] = j2;
    }
    ncnt[tid] = c;
    f_own[tid] = fsum;
  }
  for (int o = tid; o < JR * NN; o += 256) xs[o] = 1.0f / 96.0f;  // ||x0||=1

  gbar(flags, 1, blk);

  // ---- P3: recon -> fr, dR -> t2, D ----
  for (int e = tid; e < NN * NN; e += 256) {
    int a = e / NN, b = e % NN;
    int i = min(a, b), j = max(a, b);
    int k = i * NN - (i * (i - 1)) / 2 + (j - i);   // row-major triu index
    t2s[e] = ldA(&lg2[(k / LGB) * LGP + (k % LGB)]);
  }
  __syncthreads();
  if (tid < NN) {
    float s = 0.0f;
    for (int b = 0; b < NN; ++b) s += t2s[tid * NN + b];
    frs[tid] = s;
    dRs[tid] = t2s[tid * NN + tid];
  }
  __syncthreads();
  for (int e = tid; e < NN * NN; e += 256) {
    int a = e / NN, b = e % NN;
    t2s[e] = (a == b) ? 0.0f : t2s[e] * dRs[a] * dRs[b];
  }
  for (int o = tid; o < JR * NN; o += 256) {
    int il = o / NN, a = o % NN;
    Ds[o] = dRs[a] / (fabsf(f_own[il] - frs[a]) + 1.0f);
  }
  __syncthreads();

  // ---- main mpm loop: one flag barrier per iteration ----
  for (int it = 0; it < NITER; ++it) {
    float* Mw = (it & 1) ? M1 : M0;

    // Phase A: M[r][a] = max_b x[r][b]*t2[a][b], 6 rows, split-K over e8.
    if (tid < 192) {
      int aq = tid % 24;          // a-quad
      int e8 = tid / 24;          // b-range
      int b0 = e8 * 12;
      float xr[JR][12];
#pragma unroll
      for (int r = 0; r < JR; ++r)
#pragma unroll
        for (int c4 = 0; c4 < 3; ++c4) {
          float4 v = *(const float4*)&xs[r * NN + b0 + 4 * c4];
          xr[r][4 * c4 + 0] = v.x; xr[r][4 * c4 + 1] = v.y;
          xr[r][4 * c4 + 2] = v.z; xr[r][4 * c4 + 3] = v.w;
        }
      float4 acc[JR];
#pragma unroll
      for (int r = 0; r < JR; ++r) acc[r] = make_float4(0.f, 0.f, 0.f, 0.f);
#pragma unroll
      for (int c = 0; c < 12; ++c) {
        float4 t = *(const float4*)&t2s[(b0 + c) * NN + 4 * aq];
#pragma unroll
        for (int r = 0; r < JR; ++r) {
          acc[r].x = fmaxf(acc[r].x, xr[r][c] * t.x);
          acc[r].y = fmaxf(acc[r].y, xr[r][c] * t.y);
          acc[r].z = fmaxf(acc[r].z, xr[r][c] * t.z);
          acc[r].w = fmaxf(acc[r].w, xr[r][c] * t.w);
        }
      }
#pragma unroll
      for (int r = 0; r < JR; ++r)
        *(float4*)&parts[(e8 * JR + r) * NN + 4 * aq] = acc[r];
    }
    __syncthreads();
    for (int o = tid; o < JR * NN; o += 256) {
      int r = o / NN, a = o % NN;
      float m = parts[r * NN + a];
#pragma unroll
      for (int e = 1; e < 8; ++e) m = fmaxf(m, parts[(e * JR + r) * NN + a]);
      stA(&Mw[(blk * JR + r) * NN + a], m);   // sc1: straight to MALL
    }

    gbar(flags, (uint32_t)(it + 2), blk);

    // Broadcast full M into LDS: 18 independent dwordx2 sc1 loads/thread.
    {
      const unsigned long long* Mr8 = (const unsigned long long*)Mw;
      unsigned long long* Ms8 = (unsigned long long*)Ms;
#pragma unroll
      for (int e = 0; e < 18; ++e) {
        int idx = tid + 256 * e;   // 18*256 = 4608 = NN*NN/2
        Ms8[idx] = ldA64(&Mr8[idx]);
      }
    }
    if (tid == 0) {
      s_scale = (it == 0) ? 1.0f : rsqrtf(ldA(&normsq[it - 1]));
    }
    __syncthreads();

    // Phase C: u[r][a] = scale*(x[r][a]*D[r][a] + sum_{j in N(r)} M[j][a])
    float scale = s_scale;
    float nsq = 0.0f;
    for (int o = tid; o < JR * NN; o += 256) {
      int il = o / NN, a = o % NN;
      float acc = xs[o] * Ds[o];
      int cnt = ncnt[il];
      const int* nb = &nbr[il * NN];
      for (int c = 0; c < cnt; ++c)
        acc += Ms[nb[c] * NN + a];         // LDS, conflict-free
      float u = scale * acc;
      xs[o] = u;
      nsq += u * u;
    }
#pragma unroll
    for (int off = 32; off > 0; off >>= 1) nsq += __shfl_down(nsq, off);
    if ((tid & 63) == 0) red[tid >> 6] = nsq;
    __syncthreads();
    if (tid == 0) {
      float t = red[0] + red[1] + red[2] + red[3];
      __hip_atomic_fetch_add(&normsq[it], t, __ATOMIC_RELAXED,
                             __HIP_MEMORY_SCOPE_AGENT);
    }
    __syncthreads();
  }

  // ---- final exact normalization + store ----
  gbar(flags, (uint32_t)(NITER + 2), blk);
  if (tid == 0) s_scale = rsqrtf(ldA(&normsq[NITER - 1]));
  __syncthreads();
  for (int o = tid; o < JR * NN; o += 256) {
    int og = blk * JR * NN + o;
    float v = s_scale * xs[o];
    if (isf32) ((float*)out)[og] = v;
    else       ((__hip_bfloat16*)out)[og] = __float2bfloat16(v);
  }
}

extern "C" void kernel_launch(void* const* d_in, const int* in_sizes, int n_in,
                              void* d_out, int out_size, void* d_ws, size_t ws_size,
                              hipStream_t stream) {
  (void)in_sizes; (void)n_in; (void)out_size; (void)ws_size;
  hipLaunchKernelGGL(gvae_kernel, dim3(NBLK), dim3(256), 0, stream,
                     d_in[0], d_in[1], d_in[3], d_in[4], d_in[5], d_in[6],
                     d_in[7], d_in[8], d_out, (float*)d_ws);
}